// Round 11
// baseline (255.688 us; speedup 1.0000x reference)
//
#include <hip/hip_runtime.h>

// LSTM: B=1024, S=512, E=H=50, fp32 in/out.
// Grid: 256 blocks x 512 threads (8 waves, 2/SIMD). Each block owns 4 chains for all 512 steps.
// Waves 0-5: 2 M-tiles each; wave 6: 1 M-tile; wave 7: x-stager. (13 tiles cover 208 gate rows.)
// gates(16x16 tiles) = W_reordered(208x128, fp16 in VGPRs) @ [x;h] (128x16, fp16 in LDS).
// Gate reorder j = h*4 + g -> lane (kg,m)'s 4 acc regs = {i,f,g,o} of cell (chain=m, h=4*mt+kg).
// SINGLE barrier per step; activation done DIRECTLY on accumulator lanes (m<4) — no bpermute,
// no gatebuf (R8's bpermute cost ~200 cyc latency + 15M bank conflicts for an ~80-cyc issue win).
// x-part of t+1 prefetched via xcur; wave 7 stages the x ring 2 steps ahead.

typedef __attribute__((ext_vector_type(8))) _Float16 f16x8;  // 8 x fp16 (4 VGPRs) MFMA operand
typedef __attribute__((ext_vector_type(4))) float f32x4;

__device__ __forceinline__ float fast_sigmoid(float z) {
  return __builtin_amdgcn_rcpf(1.0f + __expf(-z));
}
__device__ __forceinline__ float fast_tanh(float z) {
  return 1.0f - 2.0f * __builtin_amdgcn_rcpf(1.0f + __expf(2.0f * z));
}

__global__ __launch_bounds__(512, 1) void lstm_fused(
    const float* __restrict__ xg,     // (1024, 512, 50)
    const float* __restrict__ W_ih,   // (200, 50)
    const float* __restrict__ W_hh,   // (200, 50)
    const float* __restrict__ b_ih,   // (200,)
    const float* __restrict__ b_hh,   // (200,)
    float* __restrict__ out)          // (1024, 1, 50)
{
  constexpr int S = 512, E = 50, H = 50;
  const int tid  = threadIdx.x;
  const int lane = tid & 63;
  const int wv   = tid >> 6;
  const int c0   = blockIdx.x << 2;   // 4 chains per block

  // LDS: xbuf ring[4 slots][2 kt][4 chains][64B] = 2048 B @0
  //      hbuf ring[2 slots][2 kt][4 chains][64B] = 1024 B @2048
  __shared__ __align__(16) unsigned char lds[3072];
  for (int i = tid; i < 3072 / 4; i += 512) reinterpret_cast<unsigned*>(lds)[i] = 0u;

  const int m  = lane & 15;   // A m-index / D col (chain for m<4)
  const int kg = lane >> 4;   // k-group of 8; D row-group (h-sub)
  const int tstart = 2 * wv;
  const int ntiles = (wv < 6) ? 2 : ((wv == 6) ? 1 : 0);

  // ---- W fragments: register-stationary fp16 (2 tiles/wave) ----
  f16x8 wfr[2][4];
  f32x4 bias[2];
#pragma unroll
  for (int i = 0; i < 2; ++i) {
    const int  mt    = tstart + i;
    const bool tv    = (i < ntiles);
    const int  j     = mt * 16 + m;     // reordered gate idx = h*4 + g
    const int  hh    = j >> 2, g = j & 3;
    const bool rowok = tv && (hh < H);
#pragma unroll
    for (int kt = 0; kt < 4; ++kt) {
      f16x8 s;
#pragma unroll
      for (int jj = 0; jj < 8; ++jj) {
        const int k = kt * 32 + kg * 8 + jj;
        float w = 0.0f;
        if (rowok) {
          if (k < 50)                  w = W_ih[(g * 50 + hh) * 50 + k];
          else if (k >= 64 && k < 114) w = W_hh[(g * 50 + hh) * 50 + (k - 64)];
        }
        s[jj] = (_Float16)w;
      }
      wfr[i][kt] = s;
    }
    f32x4 bv;
#pragma unroll
    for (int r = 0; r < 4; ++r) {
      const int jr = mt * 16 + kg * 4 + r;
      const int hr = jr >> 2, gr = jr & 3;
      bv[r] = (tv && hr < H) ? (b_ih[gr * 50 + hr] + b_hh[gr * 50 + hr]) : 0.0f;
    }
    bias[i] = bv;
  }

  float cst[2] = {0.f, 0.f};   // c state: cell (chain=m, h=4*(tstart+i)+kg), lanes m<4

  // ---- wave 7: x stagers (4 (chain,e) slots per lane) ----
  const bool isstg = (wv == 7);
  bool     sok[4];
  long     gb[4];
  unsigned la[4];
  float    A[4], B[4];
#pragma unroll
  for (int u = 0; u < 4; ++u) {
    const int xs = lane + 64 * u;
    sok[u] = isstg && (xs < 200);
    const int chn = sok[u] ? (xs / 50) : 0;
    const int e   = sok[u] ? (xs - 50 * chn) : 0;
    gb[u] = ((long)(c0 + chn) * S) * E + e;
    la[u] = (unsigned)(((e >> 5) << 8) + (chn << 6) + ((e & 31) << 1));
    A[u] = 0.f; B[u] = 0.f;
  }

  __syncthreads();   // zeros visible (pads + h0 = 0)

  // prime x slots 0,1; load x[2],x[3] into stage regs
#pragma unroll
  for (int u = 0; u < 4; ++u) {
    if (sok[u]) {
      *reinterpret_cast<_Float16*>(lds + 0 * 512 + la[u]) = (_Float16)xg[gb[u] + 0 * E];
      *reinterpret_cast<_Float16*>(lds + 1 * 512 + la[u]) = (_Float16)xg[gb[u] + 1 * E];
    }
  }
#pragma unroll
  for (int u = 0; u < 4; ++u) {
    if (sok[u]) { A[u] = xg[gb[u] + 2 * E]; B[u] = xg[gb[u] + 3 * E]; }
  }
  __syncthreads();   // x slots 0,1 staged

  const int      bc  = lane & 3;
  const unsigned bro = (unsigned)((bc << 6) + (kg << 4));

  // ---- prime xcur = bias + W_x @ x[0] (slot 0) ----
  f32x4 xcur[2];
  {
    const f16x8 b0 = *reinterpret_cast<const f16x8*>(lds + 0u + bro);
    const f16x8 b1 = *reinterpret_cast<const f16x8*>(lds + 256u + bro);
#pragma unroll
    for (int i = 0; i < 2; ++i) {
      f32x4 a = bias[i];
      a = __builtin_amdgcn_mfma_f32_16x16x32_f16(wfr[i][0], b0, a, 0, 0, 0);
      a = __builtin_amdgcn_mfma_f32_16x16x32_f16(wfr[i][1], b1, a, 0, 0, 0);
      xcur[i] = a;
    }
  }

  auto step = [&](int t, float (&P)[4]) {
    if (ntiles > 0) {
      const unsigned hs = 2048u + (unsigned)(t & 1) * 512u;
      const unsigned xs = (unsigned)((t + 1) & 3) * 512u;
      const f16x8 b2  = *reinterpret_cast<const f16x8*>(lds + hs + bro);
      const f16x8 b3  = *reinterpret_cast<const f16x8*>(lds + hs + 256u + bro);
      const f16x8 nb0 = *reinterpret_cast<const f16x8*>(lds + xs + bro);
      const f16x8 nb1 = *reinterpret_cast<const f16x8*>(lds + xs + 256u + bro);

      // critical path: h-part, chain depth 2, C-in = precomputed x-part
      f32x4 acc[2];
      {
        f32x4 a0 = xcur[0];
        a0 = __builtin_amdgcn_mfma_f32_16x16x32_f16(wfr[0][2], b2, a0, 0, 0, 0);
        a0 = __builtin_amdgcn_mfma_f32_16x16x32_f16(wfr[0][3], b3, a0, 0, 0, 0);
        acc[0] = a0;
        f32x4 a1 = xcur[1];
        a1 = __builtin_amdgcn_mfma_f32_16x16x32_f16(wfr[1][2], b2, a1, 0, 0, 0);
        a1 = __builtin_amdgcn_mfma_f32_16x16x32_f16(wfr[1][3], b3, a1, 0, 0, 0);
        acc[1] = a1;
      }

      // direct activation on accumulator lanes: lane (kg, m<4) owns cell (chain=m, h=4*(tstart+i)+kg)
#pragma unroll
      for (int i = 0; i < 2; ++i) {
        const int h = 4 * (tstart + i) + kg;
        if ((m < 4) && (i < ntiles) && (h < H)) {
          const float ig = fast_sigmoid(acc[i][0]);
          const float fg = fast_sigmoid(acc[i][1]);
          const float gg = fast_tanh   (acc[i][2]);
          const float og = fast_sigmoid(acc[i][3]);
          const float c  = fg * cst[i] + ig * gg;
          cst[i] = c;
          const float hv = og * fast_tanh(c);
          if (t == S - 1) {
            out[(long)(c0 + m) * H + h] = hv;
          } else {
            *reinterpret_cast<_Float16*>(
                lds + 2048u + (unsigned)((t + 1) & 1) * 512u +
                (unsigned)(((h >> 5) << 8) + (m << 6) + ((h & 31) << 1))) = (_Float16)hv;
          }
        }
      }

      // off-critical-path: x-part for step t+1
      {
        f32x4 c0v = bias[0];
        c0v = __builtin_amdgcn_mfma_f32_16x16x32_f16(wfr[0][0], nb0, c0v, 0, 0, 0);
        c0v = __builtin_amdgcn_mfma_f32_16x16x32_f16(wfr[0][1], nb1, c0v, 0, 0, 0);
        xcur[0] = c0v;
        f32x4 c1v = bias[1];
        c1v = __builtin_amdgcn_mfma_f32_16x16x32_f16(wfr[1][0], nb0, c1v, 0, 0, 0);
        c1v = __builtin_amdgcn_mfma_f32_16x16x32_f16(wfr[1][1], nb1, c1v, 0, 0, 0);
        xcur[1] = c1v;
      }
    } else if (isstg) {
      if (t + 2 < S) {
        const unsigned sl = (unsigned)((t + 2) & 3) * 512u;
#pragma unroll
        for (int u = 0; u < 4; ++u)
          if (sok[u]) *reinterpret_cast<_Float16*>(lds + sl + la[u]) = (_Float16)P[u];
        if (t + 4 < S) {
#pragma unroll
          for (int u = 0; u < 4; ++u)
            if (sok[u]) P[u] = xg[gb[u] + (long)(t + 4) * E];
        }
      }
    }
    __syncthreads();   // h slot (t+1)&1 and x slot (t+2)&3 complete
  };

  for (int t = 0; t < S; t += 2) {
    step(t, A);
    step(t + 1, B);
  }
}

extern "C" void kernel_launch(void* const* d_in, const int* in_sizes, int n_in,
                              void* d_out, int out_size, void* d_ws, size_t ws_size,
                              hipStream_t stream) {
  const float* x    = (const float*)d_in[0];
  const float* W_ih = (const float*)d_in[1];
  const float* W_hh = (const float*)d_in[2];
  const float* b_ih = (const float*)d_in[3];
  const float* b_hh = (const float*)d_in[4];
  float* out = (float*)d_out;
  hipLaunchKernelGGL(lstm_fused, dim3(256), dim3(512), 0, stream,
                     x, W_ih, W_hh, b_ih, b_hh, out);
}

// Round 14
// 200.359 us; speedup vs baseline: 1.2761x; 1.2761x over previous
//
#include <hip/hip_runtime.h>

// LSTM: B=1024, S=512, E=H=50, fp32 in/out.
// Grid: 256 blocks x 512 threads (8 waves, 2/SIMD). Each block owns 4 chains for all 512 steps.
// Waves 0-5: 2 M-tiles; wave 6: 1 M-tile; wave 7: x-stager. (13 tiles cover 208 gate rows.)
// gates(16x16 tiles) = W_reordered(208x128, fp16 in VGPRs) @ [x;h] (128x16, fp16 in LDS).
// Gate reorder j = h*4 + g -> lane (kg,m)'s 4 acc regs = {i,f,g,o} of cell (chain=m, h=4*mt+kg).
// SINGLE barrier per step. B-operand ds_reads masked to m<4 (cols 4-15 stay zero -> 4x less LDS
// traffic; MFMA is per-column independent so zero cols are benign). Tile-1 gates spread from
// lanes m=0..3 to m=4..7 via DPP row_shr:4 (0x114: lane i reads lane i-4 — R13's row_shl read
// lane i+4 = bias-garbage cols, the correctness bug). Each lane runs ONE 10-trans cell chain.
// x-part of t+1 prefetched via xcur; wave 7 stages the x ring 2 steps ahead.

typedef __attribute__((ext_vector_type(8))) _Float16 f16x8;  // 8 x fp16 (4 VGPRs) MFMA operand
typedef __attribute__((ext_vector_type(4))) float f32x4;

__device__ __forceinline__ float fast_sigmoid(float z) {
  return __builtin_amdgcn_rcpf(1.0f + __expf(-z));
}
__device__ __forceinline__ float fast_tanh(float z) {
  return 1.0f - 2.0f * __builtin_amdgcn_rcpf(1.0f + __expf(2.0f * z));
}

__global__ __launch_bounds__(512, 1) void lstm_fused(
    const float* __restrict__ xg,     // (1024, 512, 50)
    const float* __restrict__ W_ih,   // (200, 50)
    const float* __restrict__ W_hh,   // (200, 50)
    const float* __restrict__ b_ih,   // (200,)
    const float* __restrict__ b_hh,   // (200,)
    float* __restrict__ out)          // (1024, 1, 50)
{
  constexpr int S = 512, E = 50, H = 50;
  const int tid  = threadIdx.x;
  const int lane = tid & 63;
  const int wv   = tid >> 6;
  const int c0   = blockIdx.x << 2;   // 4 chains per block

  // LDS: xbuf ring[4 slots][2 kt][4 chains][64B] = 2048 B @0
  //      hbuf ring[2 slots][2 kt][4 chains][64B] = 1024 B @2048
  __shared__ __align__(16) unsigned char lds[3072];
  for (int i = tid; i < 3072 / 4; i += 512) reinterpret_cast<unsigned*>(lds)[i] = 0u;

  const int m  = lane & 15;   // A m-index / D col (chain for m<4)
  const int kg = lane >> 4;   // k-group of 8; D row-group (h-sub)
  const int tstart = 2 * wv;
  const int ntiles = (wv < 6) ? 2 : ((wv == 6) ? 1 : 0);

  // ---- W fragments: register-stationary fp16 (2 tiles/wave) ----
  f16x8 wfr[2][4];
  f32x4 bias[2];
#pragma unroll
  for (int i = 0; i < 2; ++i) {
    const int  mt    = tstart + i;
    const bool tv    = (i < ntiles);
    const int  j     = mt * 16 + m;     // reordered gate idx = h*4 + g
    const int  hh    = j >> 2, g = j & 3;
    const bool rowok = tv && (hh < H);
#pragma unroll
    for (int kt = 0; kt < 4; ++kt) {
      f16x8 s;
#pragma unroll
      for (int jj = 0; jj < 8; ++jj) {
        const int k = kt * 32 + kg * 8 + jj;
        float w = 0.0f;
        if (rowok) {
          if (k < 50)                  w = W_ih[(g * 50 + hh) * 50 + k];
          else if (k >= 64 && k < 114) w = W_hh[(g * 50 + hh) * 50 + (k - 64)];
        }
        s[jj] = (_Float16)w;
      }
      wfr[i][kt] = s;
    }
    f32x4 bv;
#pragma unroll
    for (int r = 0; r < 4; ++r) {
      const int jr = mt * 16 + kg * 4 + r;
      const int hr = jr >> 2, gr = jr & 3;
      bv[r] = (tv && hr < H) ? (b_ih[gr * 50 + hr] + b_hh[gr * 50 + hr]) : 0.0f;
    }
    bias[i] = bv;
  }

  float cst = 0.0f;   // c state: lane (kg, m<8) owns cell (chain=m&3, h=4*(tstart+(m>>2))+kg)

  // ---- wave 7: x stagers (4 (chain,e) slots per lane) ----
  const bool isstg = (wv == 7);
  bool     sok[4];
  long     gb[4];
  unsigned la[4];
  float    A[4], B[4];
#pragma unroll
  for (int u = 0; u < 4; ++u) {
    const int xs = lane + 64 * u;
    sok[u] = isstg && (xs < 200);
    const int chn = sok[u] ? (xs / 50) : 0;
    const int e   = sok[u] ? (xs - 50 * chn) : 0;
    gb[u] = ((long)(c0 + chn) * S) * E + e;
    la[u] = (unsigned)(((e >> 5) << 8) + (chn << 6) + ((e & 31) << 1));
    A[u] = 0.f; B[u] = 0.f;
  }

  __syncthreads();   // zeros visible (pads + h0 = 0)

  // prime x slots 0,1; load x[2],x[3] into stage regs
#pragma unroll
  for (int u = 0; u < 4; ++u) {
    if (sok[u]) {
      *reinterpret_cast<_Float16*>(lds + 0 * 512 + la[u]) = (_Float16)xg[gb[u] + 0 * E];
      *reinterpret_cast<_Float16*>(lds + 1 * 512 + la[u]) = (_Float16)xg[gb[u] + 1 * E];
    }
  }
#pragma unroll
  for (int u = 0; u < 4; ++u) {
    if (sok[u]) { A[u] = xg[gb[u] + 2 * E]; B[u] = xg[gb[u] + 3 * E]; }
  }
  __syncthreads();   // x slots 0,1 staged

  const unsigned bro = (unsigned)(((lane & 3) << 6) + (kg << 4));

  // B-operand registers: persistent, zero for lanes m>=4 (masked loads keep cols 4-15 zero)
  f16x8 b2{}, b3{}, nb0{}, nb1{};

  // ---- prime xcur = bias + W_x @ x[0] (slot 0) ----
  f32x4 xcur[2];
  {
    if (m < 4) {
      nb0 = *reinterpret_cast<const f16x8*>(lds + 0u + bro);
      nb1 = *reinterpret_cast<const f16x8*>(lds + 256u + bro);
    }
#pragma unroll
    for (int i = 0; i < 2; ++i) {
      f32x4 a = bias[i];
      a = __builtin_amdgcn_mfma_f32_16x16x32_f16(wfr[i][0], nb0, a, 0, 0, 0);
      a = __builtin_amdgcn_mfma_f32_16x16x32_f16(wfr[i][1], nb1, a, 0, 0, 0);
      xcur[i] = a;
    }
  }

  auto step = [&](int t, float (&P)[4]) {
    if (ntiles > 0) {
      const unsigned hs = 2048u + (unsigned)(t & 1) * 512u;
      const unsigned xs = (unsigned)((t + 1) & 3) * 512u;
      if (m < 4) {   // only real chain columns read; cols 4-15 stay zero
        b2  = *reinterpret_cast<const f16x8*>(lds + hs + bro);
        b3  = *reinterpret_cast<const f16x8*>(lds + hs + 256u + bro);
        nb0 = *reinterpret_cast<const f16x8*>(lds + xs + bro);
        nb1 = *reinterpret_cast<const f16x8*>(lds + xs + 256u + bro);
      }

      // critical path: h-part, chain depth 2, C-in = precomputed x-part
      f32x4 acc0 = xcur[0];
      acc0 = __builtin_amdgcn_mfma_f32_16x16x32_f16(wfr[0][2], b2, acc0, 0, 0, 0);
      acc0 = __builtin_amdgcn_mfma_f32_16x16x32_f16(wfr[0][3], b3, acc0, 0, 0, 0);
      f32x4 acc1 = xcur[1];
      acc1 = __builtin_amdgcn_mfma_f32_16x16x32_f16(wfr[1][2], b2, acc1, 0, 0, 0);
      acc1 = __builtin_amdgcn_mfma_f32_16x16x32_f16(wfr[1][3], b3, acc1, 0, 0, 0);

      // spread tile-1 gates from lanes m=0..3 to m=4..7 (DPP row_shr:4 -> lane i reads lane i-4)
      float gv[4];
#pragma unroll
      for (int r = 0; r < 4; ++r) {
        const int sp = __builtin_amdgcn_update_dpp(
            0, __float_as_int(acc1[r]), 0x114 /*row_shr:4*/, 0xF, 0xF, true);
        gv[r] = (m < 4) ? acc0[r] : __int_as_float(sp);
      }

      // one cell chain per lane: lanes (kg, m<8), tile ti=m>>2, chain m&3
      const int ti = m >> 2;
      const int h  = 4 * (tstart + ti) + kg;
      if ((m < 8) && (ti < ntiles) && (h < H)) {
        const float ig = fast_sigmoid(gv[0]);
        const float fg = fast_sigmoid(gv[1]);
        const float gg = fast_tanh   (gv[2]);
        const float og = fast_sigmoid(gv[3]);
        const float c  = fg * cst + ig * gg;
        cst = c;
        const float hv = og * fast_tanh(c);
        const int ch = m & 3;
        if (t == S - 1) {
          out[(long)(c0 + ch) * H + h] = hv;
        } else {
          *reinterpret_cast<_Float16*>(
              lds + 2048u + (unsigned)((t + 1) & 1) * 512u +
              (unsigned)(((h >> 5) << 8) + (ch << 6) + ((h & 31) << 1))) = (_Float16)hv;
        }
      }

      // off-critical-path: x-part for step t+1
      {
        f32x4 c0v = bias[0];
        c0v = __builtin_amdgcn_mfma_f32_16x16x32_f16(wfr[0][0], nb0, c0v, 0, 0, 0);
        c0v = __builtin_amdgcn_mfma_f32_16x16x32_f16(wfr[0][1], nb1, c0v, 0, 0, 0);
        xcur[0] = c0v;
        f32x4 c1v = bias[1];
        c1v = __builtin_amdgcn_mfma_f32_16x16x32_f16(wfr[1][0], nb0, c1v, 0, 0, 0);
        c1v = __builtin_amdgcn_mfma_f32_16x16x32_f16(wfr[1][1], nb1, c1v, 0, 0, 0);
        xcur[1] = c1v;
      }
    } else if (isstg) {
      if (t + 2 < S) {
        const unsigned sl = (unsigned)((t + 2) & 3) * 512u;
#pragma unroll
        for (int u = 0; u < 4; ++u)
          if (sok[u]) *reinterpret_cast<_Float16*>(lds + sl + la[u]) = (_Float16)P[u];
        if (t + 4 < S) {
#pragma unroll
          for (int u = 0; u < 4; ++u)
            if (sok[u]) P[u] = xg[gb[u] + (long)(t + 4) * E];
        }
      }
    }
    __syncthreads();   // h slot (t+1)&1 and x slot (t+2)&3 complete
  };

  for (int t = 0; t < S; t += 2) {
    step(t, A);
    step(t + 1, B);
  }
}

extern "C" void kernel_launch(void* const* d_in, const int* in_sizes, int n_in,
                              void* d_out, int out_size, void* d_ws, size_t ws_size,
                              hipStream_t stream) {
  const float* x    = (const float*)d_in[0];
  const float* W_ih = (const float*)d_in[1];
  const float* W_hh = (const float*)d_in[2];
  const float* b_ih = (const float*)d_in[3];
  const float* b_hh = (const float*)d_in[4];
  float* out = (float*)d_out;
  hipLaunchKernelGGL(lstm_fused, dim3(256), dim3(512), 0, stream,
                     x, W_ih, W_hh, b_ih, b_hh, out);
}